// Round 10
// baseline (1583.529 us; speedup 1.0000x reference)
//
#include <hip/hip_runtime.h>
#include <hip/hip_bf16.h>
#include <stdint.h>

#define S_LEN 4096
#define HN    32
#define SSD   64
#define KD    2048      // D_IN = H*SS = D_OUT
#define MROWS 16384     // B*S

typedef __attribute__((ext_vector_type(4))) float f32x4;
typedef __attribute__((ext_vector_type(8))) short bf16x8;
typedef __attribute__((ext_vector_type(4))) int i32x4;
typedef __attribute__((address_space(3))) char as3char;
typedef __attribute__((address_space(1))) char as1char;

__device__ __forceinline__ unsigned short f2bf(float f){
  unsigned int u = __float_as_uint(f);
  u += 0x7FFFu + ((u >> 16) & 1u);   // round-to-nearest-even
  return (unsigned short)(u >> 16);
}

// ---------------- convert f32 -> bf16 (vectorized, 4 elts/thread) ----------------
__global__ __launch_bounds__(256) void cvt_bf16_k(const float* __restrict__ src,
                                                  unsigned short* __restrict__ dst){
  int i = (blockIdx.x * 256 + threadIdx.x) * 4;
  float4 v = *(const float4*)(src + i);
  ushort4 r;
  r.x = f2bf(v.x); r.y = f2bf(v.y); r.z = f2bf(v.z); r.w = f2bf(v.w);
  *(ushort4*)(dst + i) = r;
}

// ---------------- GEMM (bf16, global_load_lds), optional bias epilogue ----------------
// C[row][col] = sum_k A[row][k]*B[col][k]  (+ bias[col] if bias != nullptr)
__global__ __launch_bounds__(256) void gemm_bf16_k(const unsigned short* __restrict__ A,
                                                   const unsigned short* __restrict__ Bw,
                                                   const float* __restrict__ bias,  // may be null
                                                   float* __restrict__ C){
  __shared__ short As[128*32];
  __shared__ short Bs[128*32];
  const int tid  = threadIdx.x;
  const int bn   = blockIdx.x & 15;
  const int bm   = blockIdx.x >> 4;
  const int lane = tid & 63;
  const int wv   = tid >> 6;
  const int wvU  = __builtin_amdgcn_readfirstlane(wv);
  const int wm   = (wv >> 1) * 64;
  const int wn   = (wv & 1) * 64;

  f32x4 acc[4][4];
#pragma unroll
  for (int i=0;i<4;i++)
#pragma unroll
    for (int j=0;j<4;j++)
#pragma unroll
      for (int q=0;q<4;q++) acc[i][j][q] = 0.0f;

  as3char* asB = (as3char*)As;
  as3char* bsB = (as3char*)Bs;
  as1char* aG  = (as1char*)A;
  as1char* bG  = (as1char*)Bw;

  const int fr  = lane & 15;
  const int fko = (lane >> 4) * 8;

  for (int kt=0; kt<KD/32; ++kt){
    __syncthreads();                 // previous tile's frag reads done
#pragma unroll
    for (int c=0;c<2;c++){
      const int off  = (wvU*2 + c)*1024 + lane*16;
      const int row  = off >> 6;
      const int colB = off & 63;
      __builtin_amdgcn_global_load_lds(
        (__attribute__((address_space(1))) void*)(aG + (size_t)(bm*128 + row)*4096 + (size_t)kt*64 + colB),
        (__attribute__((address_space(3))) void*)(asB + (wvU*2 + c)*1024),
        16, 0, 0);
      __builtin_amdgcn_global_load_lds(
        (__attribute__((address_space(1))) void*)(bG + (size_t)(bn*128 + row)*4096 + (size_t)kt*64 + colB),
        (__attribute__((address_space(3))) void*)(bsB + (wvU*2 + c)*1024),
        16, 0, 0);
    }
    __syncthreads();                 // loads landed (vmcnt drain at barrier)

    bf16x8 af[4], bq[4];
#pragma unroll
    for (int mt=0; mt<4; mt++) af[mt] = *(const bf16x8*)&As[(wm + mt*16 + fr)*32 + fko];
#pragma unroll
    for (int nt=0; nt<4; nt++) bq[nt] = *(const bf16x8*)&Bs[(wn + nt*16 + fr)*32 + fko];
#pragma unroll
    for (int mt=0; mt<4; mt++)
#pragma unroll
      for (int nt=0; nt<4; nt++)
        acc[mt][nt] = __builtin_amdgcn_mfma_f32_16x16x32_bf16(af[mt], bq[nt], acc[mt][nt], 0, 0, 0);
  }

  float bv[4] = {0.f, 0.f, 0.f, 0.f};
  if (bias){
#pragma unroll
    for (int nt=0; nt<4; nt++) bv[nt] = bias[bn*128 + wn + nt*16 + fr];
  }
#pragma unroll
  for (int mt=0; mt<4; mt++)
#pragma unroll
    for (int nt=0; nt<4; nt++){
      const int col = bn*128 + wn + nt*16 + fr;
#pragma unroll
      for (int q=0; q<4; q++){
        const int row = bm*128 + wm + mt*16 + (lane>>4)*4 + q;
        C[(size_t)row*KD + col] = acc[mt][nt][q] + bv[nt];
      }
    }
}

// ---------------- scan: y_t = tanh(W_h y_{t-1} + hx_t) ----------------
// ONE wave per (b,h) chain; lane o owns y[o] and W row o (asm-pinned, VGPR-
// resident per R8). R5-R9 invariance (~693 cyc/step across 5 different inner
// loops) points at the per-step GLOBAL STORE: loads+stores share the in-order
// vmcnt queue, so per-step waits expose store-retire latency (~500cyc) every
// iteration regardless of compute structure.
// Fix: remove stores from the serial loop. Buffer 8 steps of y (bf16) in a
// 1KB LDS tile (ds_write_b16/step), then ONE global_store_dwordx4 per lane
// per 8 steps (lane L -> row t+L/8, 16B chunk L%8). Per-step vm queue is
// loads-only -> precise waits, store retirement off the critical path.
__global__ __attribute__((amdgpu_flat_work_group_size(64, 64)))
__attribute__((amdgpu_waves_per_eu(1, 1)))
void scan_k(const float* __restrict__ hx,
            const float* __restrict__ sw,   // [32][64][64]
            const float* __restrict__ st0,  // [4][32][64]
            unsigned short* __restrict__ ybf){ // [MROWS][2048] bf16
  const int b = blockIdx.x >> 5, h = blockIdx.x & 31;
  const int lane = threadIdx.x;        // = output index o
  const f32x4* wv = (const f32x4*)(sw + ((size_t)(h*64 + lane))*64);
  f32x4 w0  = wv[0],  w1  = wv[1],  w2  = wv[2],  w3  = wv[3],
        w4  = wv[4],  w5  = wv[5],  w6  = wv[6],  w7  = wv[7],
        w8  = wv[8],  w9  = wv[9],  w10 = wv[10], w11 = wv[11],
        w12 = wv[12], w13 = wv[13], w14 = wv[14], w15 = wv[15];
  // pin: values become asm-produced -> cannot be rematerialized in-loop.
  asm volatile("" : "+v"(w0), "+v"(w1), "+v"(w2),  "+v"(w3),
                    "+v"(w4), "+v"(w5), "+v"(w6),  "+v"(w7),
                    "+v"(w8), "+v"(w9), "+v"(w10), "+v"(w11),
                    "+v"(w12),"+v"(w13),"+v"(w14), "+v"(w15));

  __shared__ __align__(16) unsigned short ybuf[8][64];   // 1KB staging tile

  float y = st0[(b*32 + h)*64 + lane];
  const float* hxp = hx + (size_t)b*S_LEN*KD + h*64 + lane;
  unsigned short* const ybase = ybf + (size_t)b*S_LEN*KD + h*64;  // chain base
  const int srow = lane >> 3;          // store: which of the 8 buffered rows
  const int scol = (lane & 7) << 3;    // store: 8-ushort (16B) chunk in row

  // 8 NAMED prefetch registers (no array -> no scratch, no dynamic index)
  float h0 = hxp[0*(size_t)KD], h1 = hxp[1*(size_t)KD],
        h2 = hxp[2*(size_t)KD], h3 = hxp[3*(size_t)KD],
        h4 = hxp[4*(size_t)KD], h5 = hxp[5*(size_t)KD],
        h6 = hxp[6*(size_t)KD], h7 = hxp[7*(size_t)KD];

#define FMA4(W, J) \
    a0 = fmaf(W[0], __int_as_float(__builtin_amdgcn_readlane(yi, (J)+0)), a0); \
    a1 = fmaf(W[1], __int_as_float(__builtin_amdgcn_readlane(yi, (J)+1)), a1); \
    a2 = fmaf(W[2], __int_as_float(__builtin_amdgcn_readlane(yi, (J)+2)), a2); \
    a3 = fmaf(W[3], __int_as_float(__builtin_amdgcn_readlane(yi, (J)+3)), a3);

#define RNN_STEP(H, J, TT) { \
    const float hxv = H; \
    { const int tn_ = ((TT) + 8 < S_LEN) ? ((TT) + 8) : (S_LEN - 1); \
      H = hxp[(size_t)tn_ * KD]; } \
    const int yi = __float_as_int(y); \
    float a0=0.f, a1=0.f, a2=0.f, a3=0.f; \
    FMA4(w0,  0)  FMA4(w1,  4)  FMA4(w2,  8)  FMA4(w3,  12) \
    FMA4(w4,  16) FMA4(w5,  20) FMA4(w6,  24) FMA4(w7,  28) \
    FMA4(w8,  32) FMA4(w9,  36) FMA4(w10, 40) FMA4(w11, 44) \
    FMA4(w12, 48) FMA4(w13, 52) FMA4(w14, 56) FMA4(w15, 60) \
    const float u = (a0 + a1) + (a2 + a3) + hxv; \
    const float e = __expf(2.0f*u); \
    y = 1.0f - 2.0f*__builtin_amdgcn_rcpf(e + 1.0f); \
    ybuf[J][lane] = f2bf(y); }

  for (int t = 0; t < S_LEN; t += 8){
    RNN_STEP(h0, 0, t+0)
    RNN_STEP(h1, 1, t+1)
    RNN_STEP(h2, 2, t+2)
    RNN_STEP(h3, 3, t+3)
    RNN_STEP(h4, 4, t+4)
    RNN_STEP(h5, 5, t+5)
    RNN_STEP(h6, 6, t+6)
    RNN_STEP(h7, 7, t+7)
    // drain the 8-step tile: one 16B store per lane (rows t..t+7)
    const i32x4 v = *(const i32x4*)&ybuf[srow][scol];
    *(i32x4*)(ybase + (size_t)(t + srow)*KD + scol) = v;
  }
#undef RNN_STEP
#undef FMA4
}

extern "C" void kernel_launch(void* const* d_in, const int* in_sizes, int n_in,
                              void* d_out, int out_size, void* d_ws, size_t ws_size,
                              hipStream_t stream) {
  const float* x      = (const float*)d_in[0];
  const float* st0    = (const float*)d_in[1];
  const float* w_in   = (const float*)d_in[2];
  const float* w_st   = (const float*)d_in[3];
  const float* b_st   = (const float*)d_in[4];
  const float* w_out  = (const float*)d_in[5];
  float* out = (float*)d_out;

  // workspace layout (209 MiB total, regions time-shared):
  //   [0,            HX_B)        hx f32 (134MB)
  //   [HX_B,         HX_B+Y_B)    phase1: x_bf16 (67MB); phase2: y_bf16 (scan overwrites)
  //   [HX_B+Y_B,     +WO_B)       phase1: w_in_bf16 (8MB); phase2: w_out_bf16
  const size_t HX_B = (size_t)MROWS * KD * 4;       // 134217728
  const size_t Y_B  = (size_t)MROWS * KD * 2;       // 67108864
  const size_t WO_B = (size_t)KD * KD * 2;          // 8388608
  if (ws_size < HX_B + Y_B + WO_B) return;          // fail loudly rather than corrupt
  char* ws = (char*)d_ws;
  float*          hx   = (float*)ws;
  unsigned short* ybf  = (unsigned short*)(ws + HX_B);   // doubles as x_bf16
  unsigned short* wbf  = (unsigned short*)(ws + HX_B + Y_B); // w_in then w_out

  // phase 1: convert x and w_in, input GEMM (+bias)
  cvt_bf16_k<<<dim3((MROWS*(size_t)KD)/1024), dim3(256), 0, stream>>>(x, ybf);
  cvt_bf16_k<<<dim3((KD*KD)/1024), dim3(256), 0, stream>>>(w_in, wbf);
  gemm_bf16_k<<<dim3((MROWS/128)*(KD/128)), dim3(256), 0, stream>>>(ybf, wbf, b_st, hx);
  // phase 2: scan (overwrites x_bf16 region with y), then output GEMM
  scan_k<<<dim3(128), dim3(64), 0, stream>>>(hx, w_st, st0, ybf);
  cvt_bf16_k<<<dim3((KD*KD)/1024), dim3(256), 0, stream>>>(w_out, wbf);
  gemm_bf16_k<<<dim3((MROWS/128)*(KD/128)), dim3(256), 0, stream>>>(ybf, wbf, nullptr, out);
}

// Round 11
// 1571.926 us; speedup vs baseline: 1.0074x; 1.0074x over previous
//
#include <hip/hip_runtime.h>
#include <hip/hip_bf16.h>
#include <stdint.h>

#define S_LEN 4096
#define HN    32
#define SSD   64
#define KD    2048      // D_IN = H*SS = D_OUT
#define MROWS 16384     // B*S

typedef __attribute__((ext_vector_type(4))) float f32x4;
typedef __attribute__((ext_vector_type(8))) short bf16x8;
typedef __attribute__((ext_vector_type(2))) int i32x2;
typedef __attribute__((address_space(3))) char as3char;
typedef __attribute__((address_space(1))) char as1char;

__device__ __forceinline__ unsigned short f2bf(float f){
  unsigned int u = __float_as_uint(f);
  u += 0x7FFFu + ((u >> 16) & 1u);   // round-to-nearest-even
  return (unsigned short)(u >> 16);
}

// ---------------- convert f32 -> bf16 (vectorized, 4 elts/thread) ----------------
__global__ __launch_bounds__(256) void cvt_bf16_k(const float* __restrict__ src,
                                                  unsigned short* __restrict__ dst){
  int i = (blockIdx.x * 256 + threadIdx.x) * 4;
  float4 v = *(const float4*)(src + i);
  ushort4 r;
  r.x = f2bf(v.x); r.y = f2bf(v.y); r.z = f2bf(v.z); r.w = f2bf(v.w);
  *(ushort4*)(dst + i) = r;
}

// ---------------- GEMM (bf16, global_load_lds), optional bias epilogue ----------------
// C[row][col] = sum_k A[row][k]*B[col][k]  (+ bias[col] if bias != nullptr)
__global__ __launch_bounds__(256) void gemm_bf16_k(const unsigned short* __restrict__ A,
                                                   const unsigned short* __restrict__ Bw,
                                                   const float* __restrict__ bias,  // may be null
                                                   float* __restrict__ C){
  __shared__ short As[128*32];
  __shared__ short Bs[128*32];
  const int tid  = threadIdx.x;
  const int bn   = blockIdx.x & 15;
  const int bm   = blockIdx.x >> 4;
  const int lane = tid & 63;
  const int wv   = tid >> 6;
  const int wvU  = __builtin_amdgcn_readfirstlane(wv);
  const int wm   = (wv >> 1) * 64;
  const int wn   = (wv & 1) * 64;

  f32x4 acc[4][4];
#pragma unroll
  for (int i=0;i<4;i++)
#pragma unroll
    for (int j=0;j<4;j++)
#pragma unroll
      for (int q=0;q<4;q++) acc[i][j][q] = 0.0f;

  as3char* asB = (as3char*)As;
  as3char* bsB = (as3char*)Bs;
  as1char* aG  = (as1char*)A;
  as1char* bG  = (as1char*)Bw;

  const int fr  = lane & 15;
  const int fko = (lane >> 4) * 8;

  for (int kt=0; kt<KD/32; ++kt){
    __syncthreads();                 // previous tile's frag reads done
#pragma unroll
    for (int c=0;c<2;c++){
      const int off  = (wvU*2 + c)*1024 + lane*16;
      const int row  = off >> 6;
      const int colB = off & 63;
      __builtin_amdgcn_global_load_lds(
        (__attribute__((address_space(1))) void*)(aG + (size_t)(bm*128 + row)*4096 + (size_t)kt*64 + colB),
        (__attribute__((address_space(3))) void*)(asB + (wvU*2 + c)*1024),
        16, 0, 0);
      __builtin_amdgcn_global_load_lds(
        (__attribute__((address_space(1))) void*)(bG + (size_t)(bn*128 + row)*4096 + (size_t)kt*64 + colB),
        (__attribute__((address_space(3))) void*)(bsB + (wvU*2 + c)*1024),
        16, 0, 0);
    }
    __syncthreads();                 // loads landed (vmcnt drain at barrier)

    bf16x8 af[4], bq[4];
#pragma unroll
    for (int mt=0; mt<4; mt++) af[mt] = *(const bf16x8*)&As[(wm + mt*16 + fr)*32 + fko];
#pragma unroll
    for (int nt=0; nt<4; nt++) bq[nt] = *(const bf16x8*)&Bs[(wn + nt*16 + fr)*32 + fko];
#pragma unroll
    for (int mt=0; mt<4; mt++)
#pragma unroll
      for (int nt=0; nt<4; nt++)
        acc[mt][nt] = __builtin_amdgcn_mfma_f32_16x16x32_bf16(af[mt], bq[nt], acc[mt][nt], 0, 0, 0);
  }

  float bv[4] = {0.f, 0.f, 0.f, 0.f};
  if (bias){
#pragma unroll
    for (int nt=0; nt<4; nt++) bv[nt] = bias[bn*128 + wn + nt*16 + fr];
  }
#pragma unroll
  for (int mt=0; mt<4; mt++)
#pragma unroll
    for (int nt=0; nt<4; nt++){
      const int col = bn*128 + wn + nt*16 + fr;
#pragma unroll
      for (int q=0; q<4; q++){
        const int row = bm*128 + wm + mt*16 + (lane>>4)*4 + q;
        C[(size_t)row*KD + col] = acc[mt][nt][q] + bv[nt];
      }
    }
}

// ---------------- scan: y_t = tanh(W_h y_{t-1} + hx_t) ----------------
// ONE wave per (b,h) chain; lane o owns y[o] and W row o (asm-pinned,
// VGPR-resident per R8). R5-R10: dur invariant (~690 cyc/step) under weight
// residency / prefetch / store-placement changes -> the untouched common
// factor is the 64 interleaved v_readlane+v_fmac pairs. v_readlane is VALU-
// writes-SGPR; the immediately-following VALU SGPR read hits a HW hazard
// (~5-7 stall cyc each, un-hidable single-wave): 64x(2+2+7) ~ 690. Fix:
// PHASE-SPLIT schedule, 16 readlanes (independent, back-to-back) ->
// sched_barrier(0) -> 16 FMAs. Hazard paid 4x/step instead of 64x.
__global__ __attribute__((amdgpu_flat_work_group_size(64, 64)))
__attribute__((amdgpu_waves_per_eu(1, 1)))
void scan_k(const float* __restrict__ hx,
            const float* __restrict__ sw,   // [32][64][64]
            const float* __restrict__ st0,  // [4][32][64]
            unsigned short* __restrict__ ybf){ // [MROWS][2048] bf16
  const int b = blockIdx.x >> 5, h = blockIdx.x & 31;
  const int lane = threadIdx.x;        // = output index o
  const f32x4* wv = (const f32x4*)(sw + ((size_t)(h*64 + lane))*64);
  f32x4 w0  = wv[0],  w1  = wv[1],  w2  = wv[2],  w3  = wv[3],
        w4  = wv[4],  w5  = wv[5],  w6  = wv[6],  w7  = wv[7],
        w8  = wv[8],  w9  = wv[9],  w10 = wv[10], w11 = wv[11],
        w12 = wv[12], w13 = wv[13], w14 = wv[14], w15 = wv[15];
  // pin: values become asm-produced -> cannot be rematerialized in-loop.
  asm volatile("" : "+v"(w0), "+v"(w1), "+v"(w2),  "+v"(w3),
                    "+v"(w4), "+v"(w5), "+v"(w6),  "+v"(w7),
                    "+v"(w8), "+v"(w9), "+v"(w10), "+v"(w11),
                    "+v"(w12),"+v"(w13),"+v"(w14), "+v"(w15));

  __shared__ __align__(16) unsigned short ybuf[4][64];   // 512B staging tile

  float y = st0[(b*32 + h)*64 + lane];
  const float* hxp = hx + (size_t)b*S_LEN*KD + h*64 + lane;
  unsigned short* const ybase = ybf + (size_t)b*S_LEN*KD + h*64;  // chain base
  const int srow = lane >> 4;          // drain: buffered row (0..3)
  const int scol = (lane & 15) << 2;   // drain: 4-ushort (8B) chunk in row

  // 4 NAMED prefetch registers (no array -> no scratch, no dynamic index)
  float h0 = hxp[0*(size_t)KD], h1 = hxp[1*(size_t)KD],
        h2 = hxp[2*(size_t)KD], h3 = hxp[3*(size_t)KD];

// group G: y indices G*16..G*16+15; a_{j&3} += W_{G*4+(j>>2)}[j&3] * y[G*16+j]
#define RLGROUP(G, W0_, W1_, W2_, W3_) { \
    const float s0  = __int_as_float(__builtin_amdgcn_readlane(yi, (G)*16+ 0)); \
    const float s1  = __int_as_float(__builtin_amdgcn_readlane(yi, (G)*16+ 1)); \
    const float s2  = __int_as_float(__builtin_amdgcn_readlane(yi, (G)*16+ 2)); \
    const float s3  = __int_as_float(__builtin_amdgcn_readlane(yi, (G)*16+ 3)); \
    const float s4  = __int_as_float(__builtin_amdgcn_readlane(yi, (G)*16+ 4)); \
    const float s5  = __int_as_float(__builtin_amdgcn_readlane(yi, (G)*16+ 5)); \
    const float s6  = __int_as_float(__builtin_amdgcn_readlane(yi, (G)*16+ 6)); \
    const float s7  = __int_as_float(__builtin_amdgcn_readlane(yi, (G)*16+ 7)); \
    const float s8  = __int_as_float(__builtin_amdgcn_readlane(yi, (G)*16+ 8)); \
    const float s9  = __int_as_float(__builtin_amdgcn_readlane(yi, (G)*16+ 9)); \
    const float s10 = __int_as_float(__builtin_amdgcn_readlane(yi, (G)*16+10)); \
    const float s11 = __int_as_float(__builtin_amdgcn_readlane(yi, (G)*16+11)); \
    const float s12 = __int_as_float(__builtin_amdgcn_readlane(yi, (G)*16+12)); \
    const float s13 = __int_as_float(__builtin_amdgcn_readlane(yi, (G)*16+13)); \
    const float s14 = __int_as_float(__builtin_amdgcn_readlane(yi, (G)*16+14)); \
    const float s15 = __int_as_float(__builtin_amdgcn_readlane(yi, (G)*16+15)); \
    __builtin_amdgcn_sched_barrier(0); \
    a0 = fmaf(W0_[0], s0,  a0); a1 = fmaf(W0_[1], s1,  a1); \
    a2 = fmaf(W0_[2], s2,  a2); a3 = fmaf(W0_[3], s3,  a3); \
    a0 = fmaf(W1_[0], s4,  a0); a1 = fmaf(W1_[1], s5,  a1); \
    a2 = fmaf(W1_[2], s6,  a2); a3 = fmaf(W1_[3], s7,  a3); \
    a0 = fmaf(W2_[0], s8,  a0); a1 = fmaf(W2_[1], s9,  a1); \
    a2 = fmaf(W2_[2], s10, a2); a3 = fmaf(W2_[3], s11, a3); \
    a0 = fmaf(W3_[0], s12, a0); a1 = fmaf(W3_[1], s13, a1); \
    a2 = fmaf(W3_[2], s14, a2); a3 = fmaf(W3_[3], s15, a3); \
    __builtin_amdgcn_sched_barrier(0); }

#define RNN_STEP(H, J, TT) { \
    const float hxv = H; \
    { const int tn_ = ((TT) + 4 < S_LEN) ? ((TT) + 4) : (S_LEN - 1); \
      H = hxp[(size_t)tn_ * KD]; } \
    const int yi = __float_as_int(y); \
    float a0=0.f, a1=0.f, a2=0.f, a3=0.f; \
    RLGROUP(0, w0,  w1,  w2,  w3)  \
    RLGROUP(1, w4,  w5,  w6,  w7)  \
    RLGROUP(2, w8,  w9,  w10, w11) \
    RLGROUP(3, w12, w13, w14, w15) \
    const float u = (a0 + a1) + (a2 + a3) + hxv; \
    const float e = __expf(2.0f*u); \
    y = 1.0f - 2.0f*__builtin_amdgcn_rcpf(e + 1.0f); \
    ybuf[J][lane] = f2bf(y); }

  for (int t = 0; t < S_LEN; t += 4){
    RNN_STEP(h0, 0, t+0)
    RNN_STEP(h1, 1, t+1)
    RNN_STEP(h2, 2, t+2)
    RNN_STEP(h3, 3, t+3)
    // drain the 4-step tile: one 8B store per lane (rows t..t+3)
    const i32x2 v = *(const i32x2*)&ybuf[srow][scol];
    *(i32x2*)(ybase + (size_t)(t + srow)*KD + scol) = v;
  }
#undef RNN_STEP
#undef RLGROUP
}

extern "C" void kernel_launch(void* const* d_in, const int* in_sizes, int n_in,
                              void* d_out, int out_size, void* d_ws, size_t ws_size,
                              hipStream_t stream) {
  const float* x      = (const float*)d_in[0];
  const float* st0    = (const float*)d_in[1];
  const float* w_in   = (const float*)d_in[2];
  const float* w_st   = (const float*)d_in[3];
  const float* b_st   = (const float*)d_in[4];
  const float* w_out  = (const float*)d_in[5];
  float* out = (float*)d_out;

  // workspace layout (209 MiB total, regions time-shared):
  //   [0,            HX_B)        hx f32 (134MB)
  //   [HX_B,         HX_B+Y_B)    phase1: x_bf16 (67MB); phase2: y_bf16 (scan overwrites)
  //   [HX_B+Y_B,     +WO_B)       phase1: w_in_bf16 (8MB); phase2: w_out_bf16
  const size_t HX_B = (size_t)MROWS * KD * 4;       // 134217728
  const size_t Y_B  = (size_t)MROWS * KD * 2;       // 67108864
  const size_t WO_B = (size_t)KD * KD * 2;          // 8388608
  if (ws_size < HX_B + Y_B + WO_B) return;          // fail loudly rather than corrupt
  char* ws = (char*)d_ws;
  float*          hx   = (float*)ws;
  unsigned short* ybf  = (unsigned short*)(ws + HX_B);   // doubles as x_bf16
  unsigned short* wbf  = (unsigned short*)(ws + HX_B + Y_B); // w_in then w_out

  // phase 1: convert x and w_in, input GEMM (+bias)
  cvt_bf16_k<<<dim3((MROWS*(size_t)KD)/1024), dim3(256), 0, stream>>>(x, ybf);
  cvt_bf16_k<<<dim3((KD*KD)/1024), dim3(256), 0, stream>>>(w_in, wbf);
  gemm_bf16_k<<<dim3((MROWS/128)*(KD/128)), dim3(256), 0, stream>>>(ybf, wbf, b_st, hx);
  // phase 2: scan (overwrites x_bf16 region with y), then output GEMM
  scan_k<<<dim3(128), dim3(64), 0, stream>>>(hx, w_st, st0, ybf);
  cvt_bf16_k<<<dim3((KD*KD)/1024), dim3(256), 0, stream>>>(w_out, wbf);
  gemm_bf16_k<<<dim3((MROWS/128)*(KD/128)), dim3(256), 0, stream>>>(ybf, wbf, nullptr, out);
}

// Round 12
// 1200.681 us; speedup vs baseline: 1.3189x; 1.3092x over previous
//
#include <hip/hip_runtime.h>
#include <hip/hip_bf16.h>
#include <stdint.h>

#define S_LEN 4096
#define HN    32
#define SSD   64
#define KD    2048      // D_IN = H*SS = D_OUT
#define MROWS 16384     // B*S

typedef __attribute__((ext_vector_type(4))) float f32x4;
typedef __attribute__((ext_vector_type(8))) short bf16x8;
typedef __attribute__((ext_vector_type(2))) int i32x2;
typedef __attribute__((ext_vector_type(2))) _Float16 f16x2;
typedef __attribute__((address_space(3))) char as3char;
typedef __attribute__((address_space(1))) char as1char;

__device__ __forceinline__ unsigned short f2bf(float f){
  unsigned int u = __float_as_uint(f);
  u += 0x7FFFu + ((u >> 16) & 1u);   // round-to-nearest-even
  return (unsigned short)(u >> 16);
}

__device__ __forceinline__ f16x2 bc_h2(int v){
  union { int i; f16x2 h; } u; u.i = v; return u.h;
}

// ---------------- convert f32 -> bf16 (vectorized, 4 elts/thread) ----------------
__global__ __launch_bounds__(256) void cvt_bf16_k(const float* __restrict__ src,
                                                  unsigned short* __restrict__ dst){
  int i = (blockIdx.x * 256 + threadIdx.x) * 4;
  float4 v = *(const float4*)(src + i);
  ushort4 r;
  r.x = f2bf(v.x); r.y = f2bf(v.y); r.z = f2bf(v.z); r.w = f2bf(v.w);
  *(ushort4*)(dst + i) = r;
}

// ---------------- GEMM (bf16, global_load_lds), optional bias epilogue ----------------
__global__ __launch_bounds__(256) void gemm_bf16_k(const unsigned short* __restrict__ A,
                                                   const unsigned short* __restrict__ Bw,
                                                   const float* __restrict__ bias,  // may be null
                                                   float* __restrict__ C){
  __shared__ short As[128*32];
  __shared__ short Bs[128*32];
  const int tid  = threadIdx.x;
  const int bn   = blockIdx.x & 15;
  const int bm   = blockIdx.x >> 4;
  const int lane = tid & 63;
  const int wv   = tid >> 6;
  const int wvU  = __builtin_amdgcn_readfirstlane(wv);
  const int wm   = (wv >> 1) * 64;
  const int wn   = (wv & 1) * 64;

  f32x4 acc[4][4];
#pragma unroll
  for (int i=0;i<4;i++)
#pragma unroll
    for (int j=0;j<4;j++)
#pragma unroll
      for (int q=0;q<4;q++) acc[i][j][q] = 0.0f;

  as3char* asB = (as3char*)As;
  as3char* bsB = (as3char*)Bs;
  as1char* aG  = (as1char*)A;
  as1char* bG  = (as1char*)Bw;

  const int fr  = lane & 15;
  const int fko = (lane >> 4) * 8;

  for (int kt=0; kt<KD/32; ++kt){
    __syncthreads();                 // previous tile's frag reads done
#pragma unroll
    for (int c=0;c<2;c++){
      const int off  = (wvU*2 + c)*1024 + lane*16;
      const int row  = off >> 6;
      const int colB = off & 63;
      __builtin_amdgcn_global_load_lds(
        (__attribute__((address_space(1))) void*)(aG + (size_t)(bm*128 + row)*4096 + (size_t)kt*64 + colB),
        (__attribute__((address_space(3))) void*)(asB + (wvU*2 + c)*1024),
        16, 0, 0);
      __builtin_amdgcn_global_load_lds(
        (__attribute__((address_space(1))) void*)(bG + (size_t)(bn*128 + row)*4096 + (size_t)kt*64 + colB),
        (__attribute__((address_space(3))) void*)(bsB + (wvU*2 + c)*1024),
        16, 0, 0);
    }
    __syncthreads();                 // loads landed (vmcnt drain at barrier)

    bf16x8 af[4], bq[4];
#pragma unroll
    for (int mt=0; mt<4; mt++) af[mt] = *(const bf16x8*)&As[(wm + mt*16 + fr)*32 + fko];
#pragma unroll
    for (int nt=0; nt<4; nt++) bq[nt] = *(const bf16x8*)&Bs[(wn + nt*16 + fr)*32 + fko];
#pragma unroll
    for (int mt=0; mt<4; mt++)
#pragma unroll
      for (int nt=0; nt<4; nt++)
        acc[mt][nt] = __builtin_amdgcn_mfma_f32_16x16x32_bf16(af[mt], bq[nt], acc[mt][nt], 0, 0, 0);
  }

  float bv[4] = {0.f, 0.f, 0.f, 0.f};
  if (bias){
#pragma unroll
    for (int nt=0; nt<4; nt++) bv[nt] = bias[bn*128 + wn + nt*16 + fr];
  }
#pragma unroll
  for (int mt=0; mt<4; mt++)
#pragma unroll
    for (int nt=0; nt<4; nt++){
      const int col = bn*128 + wn + nt*16 + fr;
#pragma unroll
      for (int q=0; q<4; q++){
        const int row = bm*128 + wm + mt*16 + (lane>>4)*4 + q;
        C[(size_t)row*KD + col] = acc[mt][nt][q] + bv[nt];
      }
    }
}

// ---------------- scan: y_t = tanh(W_h y_{t-1} + hx_t) ----------------
// ONE wave per (b,h) chain; lane o owns y[o] and W row o.
// R5-R11: step time (~693 cyc) is issue-bound on ~290 VALU instrs/step;
// scheduling/residency/store changes were all no-ops. This round HALVES the
// core op count with v_dot2_f32_f16 (__builtin_amdgcn_fdot2): y kept packed
// as f16 PAIRS in one 32-bit reg -> 32 readlanes + 32 dot2 (was 64+64).
// Pair-packing is LDS-free via DPP quad_perm [1,0,3,2] (neighbor's f16);
// only even lanes' packs are consumed by readlane, so lane order is correct.
// Weights: 32 named asm-pinned f16x2 (pre-packed once). Accum stays f32.
__global__ __attribute__((amdgpu_flat_work_group_size(64, 64)))
__attribute__((amdgpu_waves_per_eu(1, 1)))
void scan_k(const float* __restrict__ hx,
            const float* __restrict__ sw,   // [32][64][64]
            const float* __restrict__ st0,  // [4][32][64]
            unsigned short* __restrict__ ybf){ // [MROWS][2048] bf16
  const int b = blockIdx.x >> 5, h = blockIdx.x & 31;
  const int lane = threadIdx.x;        // = output index o
  const f32x4* wv = (const f32x4*)(sw + ((size_t)(h*64 + lane))*64);

  // pack W row into 32 named f16x2 (pairs (2k,2k+1))
#define MKP(Q, PA, PB) { f32x4 q_ = wv[Q]; \
    PA = f16x2{(_Float16)q_[0], (_Float16)q_[1]}; \
    PB = f16x2{(_Float16)q_[2], (_Float16)q_[3]}; }
  f16x2 p0,p1,p2,p3,p4,p5,p6,p7,p8,p9,p10,p11,p12,p13,p14,p15,
        p16,p17,p18,p19,p20,p21,p22,p23,p24,p25,p26,p27,p28,p29,p30,p31;
  MKP(0,p0,p1)   MKP(1,p2,p3)   MKP(2,p4,p5)   MKP(3,p6,p7)
  MKP(4,p8,p9)   MKP(5,p10,p11) MKP(6,p12,p13) MKP(7,p14,p15)
  MKP(8,p16,p17) MKP(9,p18,p19) MKP(10,p20,p21)MKP(11,p22,p23)
  MKP(12,p24,p25)MKP(13,p26,p27)MKP(14,p28,p29)MKP(15,p30,p31)
#undef MKP
  // pin (<=16 operands per asm)
  asm volatile("" : "+v"(p0),"+v"(p1),"+v"(p2),"+v"(p3),"+v"(p4),"+v"(p5),
                    "+v"(p6),"+v"(p7),"+v"(p8),"+v"(p9),"+v"(p10),"+v"(p11),
                    "+v"(p12),"+v"(p13),"+v"(p14),"+v"(p15));
  asm volatile("" : "+v"(p16),"+v"(p17),"+v"(p18),"+v"(p19),"+v"(p20),"+v"(p21),
                    "+v"(p22),"+v"(p23),"+v"(p24),"+v"(p25),"+v"(p26),"+v"(p27),
                    "+v"(p28),"+v"(p29),"+v"(p30),"+v"(p31));

  __shared__ __align__(16) unsigned short ybuf[4][64];   // 512B staging tile

  float y = st0[(b*32 + h)*64 + lane];
  const float* hxp = hx + (size_t)b*S_LEN*KD + h*64 + lane;
  unsigned short* const ybase = ybf + (size_t)b*S_LEN*KD + h*64;  // chain base
  const int srow = lane >> 4;          // drain: buffered row (0..3)
  const int scol = (lane & 15) << 2;   // drain: 4-ushort (8B) chunk in row

  // packed f16 pair reg: lo = y[even lane of pair], hi = y[odd]. Only even
  // lanes' packs are read (readlane idx 2k), where own=lo is correct.
  unsigned hb0 = (unsigned)__builtin_bit_cast(unsigned short, (_Float16)y);
  int nb0 = __builtin_amdgcn_update_dpp(0, (int)hb0, 0xB1, 0xF, 0xF, true);
  int yp = (int)(hb0 | ((unsigned)nb0 << 16));

  // 4 NAMED prefetch registers
  float h0 = hxp[0*(size_t)KD], h1 = hxp[1*(size_t)KD],
        h2 = hxp[2*(size_t)KD], h3 = hxp[3*(size_t)KD];

// group G (pairs 8G..8G+7): 8 readlanes (lanes 16G+2j), fence, 8 dot2
#define DOT8(G, P0,P1,P2,P3,P4,P5,P6,P7) { \
    const int t0 = __builtin_amdgcn_readlane(yp, (G)*16+ 0); \
    const int t1 = __builtin_amdgcn_readlane(yp, (G)*16+ 2); \
    const int t2 = __builtin_amdgcn_readlane(yp, (G)*16+ 4); \
    const int t3 = __builtin_amdgcn_readlane(yp, (G)*16+ 6); \
    const int t4 = __builtin_amdgcn_readlane(yp, (G)*16+ 8); \
    const int t5 = __builtin_amdgcn_readlane(yp, (G)*16+10); \
    const int t6 = __builtin_amdgcn_readlane(yp, (G)*16+12); \
    const int t7 = __builtin_amdgcn_readlane(yp, (G)*16+14); \
    __builtin_amdgcn_sched_barrier(0); \
    a0 = __builtin_amdgcn_fdot2(P0, bc_h2(t0), a0, false); \
    a1 = __builtin_amdgcn_fdot2(P1, bc_h2(t1), a1, false); \
    a2 = __builtin_amdgcn_fdot2(P2, bc_h2(t2), a2, false); \
    a3 = __builtin_amdgcn_fdot2(P3, bc_h2(t3), a3, false); \
    a0 = __builtin_amdgcn_fdot2(P4, bc_h2(t4), a0, false); \
    a1 = __builtin_amdgcn_fdot2(P5, bc_h2(t5), a1, false); \
    a2 = __builtin_amdgcn_fdot2(P6, bc_h2(t6), a2, false); \
    a3 = __builtin_amdgcn_fdot2(P7, bc_h2(t7), a3, false); \
    __builtin_amdgcn_sched_barrier(0); }

#define RNN_STEP(H, J, TT) { \
    const float hxv = H; \
    { const int tn_ = ((TT) + 4 < S_LEN) ? ((TT) + 4) : (S_LEN - 1); \
      H = hxp[(size_t)tn_ * KD]; } \
    float a0=0.f, a1=0.f, a2=0.f, a3=0.f; \
    DOT8(0, p0,p1,p2,p3,p4,p5,p6,p7) \
    DOT8(1, p8,p9,p10,p11,p12,p13,p14,p15) \
    DOT8(2, p16,p17,p18,p19,p20,p21,p22,p23) \
    DOT8(3, p24,p25,p26,p27,p28,p29,p30,p31) \
    const float u = (a0 + a1) + (a2 + a3) + hxv; \
    const float e = __expf(2.0f*u); \
    y = 1.0f - 2.0f*__builtin_amdgcn_rcpf(e + 1.0f); \
    ybuf[J][lane] = f2bf(y); \
    { const unsigned hb = (unsigned)__builtin_bit_cast(unsigned short, (_Float16)y); \
      const int nb = __builtin_amdgcn_update_dpp(0, (int)hb, 0xB1, 0xF, 0xF, true); \
      yp = (int)(hb | ((unsigned)nb << 16)); } }

  for (int t = 0; t < S_LEN; t += 4){
    RNN_STEP(h0, 0, t+0)
    RNN_STEP(h1, 1, t+1)
    RNN_STEP(h2, 2, t+2)
    RNN_STEP(h3, 3, t+3)
    // drain the 4-step tile: one 8B store per lane (rows t..t+3)
    const i32x2 v = *(const i32x2*)&ybuf[srow][scol];
    *(i32x2*)(ybase + (size_t)(t + srow)*KD + scol) = v;
  }
#undef RNN_STEP
#undef DOT8
}

extern "C" void kernel_launch(void* const* d_in, const int* in_sizes, int n_in,
                              void* d_out, int out_size, void* d_ws, size_t ws_size,
                              hipStream_t stream) {
  const float* x      = (const float*)d_in[0];
  const float* st0    = (const float*)d_in[1];
  const float* w_in   = (const float*)d_in[2];
  const float* w_st   = (const float*)d_in[3];
  const float* b_st   = (const float*)d_in[4];
  const float* w_out  = (const float*)d_in[5];
  float* out = (float*)d_out;

  const size_t HX_B = (size_t)MROWS * KD * 4;       // 134217728
  const size_t Y_B  = (size_t)MROWS * KD * 2;       // 67108864
  const size_t WO_B = (size_t)KD * KD * 2;          // 8388608
  if (ws_size < HX_B + Y_B + WO_B) return;          // fail loudly rather than corrupt
  char* ws = (char*)d_ws;
  float*          hx   = (float*)ws;
  unsigned short* ybf  = (unsigned short*)(ws + HX_B);   // doubles as x_bf16
  unsigned short* wbf  = (unsigned short*)(ws + HX_B + Y_B); // w_in then w_out

  // phase 1: convert x and w_in, input GEMM (+bias)
  cvt_bf16_k<<<dim3((MROWS*(size_t)KD)/1024), dim3(256), 0, stream>>>(x, ybf);
  cvt_bf16_k<<<dim3((KD*KD)/1024), dim3(256), 0, stream>>>(w_in, wbf);
  gemm_bf16_k<<<dim3((MROWS/128)*(KD/128)), dim3(256), 0, stream>>>(ybf, wbf, b_st, hx);
  // phase 2: scan (overwrites x_bf16 region with y), then output GEMM
  scan_k<<<dim3(128), dim3(64), 0, stream>>>(hx, w_st, st0, ybf);
  cvt_bf16_k<<<dim3((KD*KD)/1024), dim3(256), 0, stream>>>(w_out, wbf);
  gemm_bf16_k<<<dim3((MROWS/128)*(KD/128)), dim3(256), 0, stream>>>(ybf, wbf, nullptr, out);
}